// Round 6
// baseline (1027.104 us; speedup 1.0000x reference)
//
#include <hip/hip_runtime.h>

#define B_ROWS 1024
#define D_DIM  512
#define C_CLS  100000
#define N_TILES 782     // ceil(100000/128)

typedef unsigned short u16;
typedef __attribute__((ext_vector_type(8))) short bf16x8;
typedef __attribute__((ext_vector_type(4))) float f32x4;

__device__ __forceinline__ u16 f2bf(float f) {
  unsigned u = __float_as_uint(f);
  u += 0x7fffu + ((u >> 16) & 1u);   // round-to-nearest-even
  return (u16)(u >> 16);
}

// pack 8 fp32 -> 8 bf16 (RTZ: take high 16 bits) via v_perm_b32
__device__ __forceinline__ bf16x8 pack8(float4 a, float4 b) {
  union { bf16x8 v; unsigned u[4]; } r;
  r.u[0] = __builtin_amdgcn_perm(__float_as_uint(a.y), __float_as_uint(a.x), 0x07060302u);
  r.u[1] = __builtin_amdgcn_perm(__float_as_uint(a.w), __float_as_uint(a.z), 0x07060302u);
  r.u[2] = __builtin_amdgcn_perm(__float_as_uint(b.y), __float_as_uint(b.x), 0x07060302u);
  r.u[3] = __builtin_amdgcn_perm(__float_as_uint(b.w), __float_as_uint(b.z), 0x07060302u);
  return r.v;
}

__device__ __forceinline__ void gll16(const void* g, void* l) {
  __builtin_amdgcn_global_load_lds(
      (const __attribute__((address_space(1))) unsigned int*)g,
      (__attribute__((address_space(3))) unsigned int*)l, 16, 0, 0);
}

// One wave per row: L2-normalize a 512-float row, emit bf16 (features only).
__global__ void norm_feat_kernel(const float* __restrict__ in, u16* __restrict__ out)
{
  const int row  = blockIdx.x * 4 + (threadIdx.x >> 6);
  const int lane = threadIdx.x & 63;
  const float4* r = (const float4*)(in + (size_t)row * D_DIM);
  float4 v0 = r[lane];
  float4 v1 = r[lane + 64];
  float ss = v0.x*v0.x + v0.y*v0.y + v0.z*v0.z + v0.w*v0.w
           + v1.x*v1.x + v1.y*v1.y + v1.z*v1.z + v1.w*v1.w;
#pragma unroll
  for (int m = 1; m < 64; m <<= 1) ss += __shfl_xor(ss, m);
  const float inv = 1.0f / fmaxf(sqrtf(ss), 1e-12f);
  ushort4 o0, o1;
  o0.x = f2bf(v0.x * inv); o0.y = f2bf(v0.y * inv);
  o0.z = f2bf(v0.z * inv); o0.w = f2bf(v0.w * inv);
  o1.x = f2bf(v1.x * inv); o1.y = f2bf(v1.y * inv);
  o1.z = f2bf(v1.z * inv); o1.w = f2bf(v1.w * inv);
  ushort4* orow = (ushort4*)(out + (size_t)row * D_DIM);
  orow[lane]      = o0;
  orow[lane + 64] = o1;
}

// W-resident GEMM: one block per 128-wide N-tile. The block stages its full
// W tile (128 x 512) ONCE -- fp32 loads, in-register ssq + bf16 pack -> 128 KB
// LDS -- then loops the 8 M-tiles of the verified 128x128 K-loop, staging only
// A (8 KB/iter, L2-hot) via double-buffered gll16. W is read from HBM exactly
// once chip-wide (205 MB); the per-iter barrier waits only on small A loads.
// Per-row 1/||w|| from fp32 ssq (cosine is scale-invariant) -> no W prep pass.
// LDS 148 KB -> 1 block/CU (4 waves); MFMA pipe is CU-shared so 4 waves can
// still approach the MFMA floor. Fused ArcFace margin + exp + row partials.
__global__ __launch_bounds__(256, 1) void arc_gemm(
    const u16* __restrict__ fn, const float* __restrict__ wt,
    const int* __restrict__ targets, float* __restrict__ psum,
    float* __restrict__ tlogit)
{
  __shared__ u16 Wlds[128 * D_DIM];   // 128 KB, bf16, XOR-swizzled k-chunks
  __shared__ u16 As[2][4096];         // 16 KB: 128 x 32 bf16, double-buffered
  __shared__ float winv[128];

  const int tid = threadIdx.x;
  const int tile_n = blockIdx.x << 7;

  const int wave = tid >> 6, lane = tid & 63;
  const int wm = wave >> 1, wno = wave & 1;
  const int quad = lane >> 4, l15 = lane & 15;

  // ---- W staging: wave handles rows wave, wave+4, ..., batched 8 rows for
  // ILP (16 outstanding float4 loads). lane covers k = lane*8..lane*8+7.
  // LDS slot for 16B chunk c of row r is c ^ (r&7) -> breaks the 1024B-row-
  // stride bank degeneracy on both write and read sides (2-way max = free).
  for (int j0 = 0; j0 < 32; j0 += 8) {
    float4 va[8], vb[8];
#pragma unroll
    for (int j = 0; j < 8; j++) {
      const int r = (j0 + j) * 4 + wave;
      const int wr = min(tile_n + r, C_CLS - 1);   // clamp pad rows (masked later)
      const float* src = wt + (size_t)wr * D_DIM + lane * 8;
      va[j] = *(const float4*)src;
      vb[j] = *(const float4*)(src + 4);
    }
#pragma unroll
    for (int j = 0; j < 8; j++) {
      const int r = (j0 + j) * 4 + wave;
      float s = va[j].x*va[j].x + va[j].y*va[j].y + va[j].z*va[j].z + va[j].w*va[j].w
              + vb[j].x*vb[j].x + vb[j].y*vb[j].y + vb[j].z*vb[j].z + vb[j].w*vb[j].w;
#pragma unroll
      for (int m = 1; m < 64; m <<= 1) s += __shfl_xor(s, m);
      if (lane == 0) winv[r] = 1.0f / fmaxf(sqrtf(s), 1e-12f);
      *(bf16x8*)&Wlds[r * D_DIM + ((lane ^ (r & 7)) * 8)] = pack8(va[j], vb[j]);
    }
  }

  // ---- A staging (round-3 verified pattern) ----
  const int srow   = tid >> 2;
  const int schunk = (tid & 3) ^ ((tid >> 3) & 3);
  const u16* Agb = fn + (size_t)srow * D_DIM + schunk * 8;
  const int ldst = tid * 8;
  const int rsw = (quad ^ ((l15 >> 1) & 3)) * 8;
  const int ra  = (wm * 64 + l15) * 32 + rsw;

  gll16(Agb,              &As[0][ldst]);
  gll16(Agb + 64 * D_DIM, &As[0][2048 + ldst]);

  __syncthreads();   // winv + Wlds ready (A buf 0 gated by loop-top barrier)

  float wiv[4];
#pragma unroll
  for (int rn = 0; rn < 4; rn++) wiv[rn] = winv[wno * 64 + rn * 16 + l15];

  const f32x4 vzero = {0.f, 0.f, 0.f, 0.f};
  f32x4 acc[4][4] = {};

  const float Sc   = 30.0f;
  const float COSM = 0.9553364891256060f;
  const float SINM = 0.2955202066613396f;
  const float THc  = -0.9553364891256060f;
  const float MMc  = 0.0886560619984019f;

  // flat (m, k) iteration: it = mi*16 + ki
  for (int it = 0; it < 128; ++it) {
    __syncthreads();   // As[it&1] ready; protects As[(it+1)&1] from overwrite
    if (it < 127) {    // prefetch next (m,k) A-slice into the other buffer
      const int nb  = (it + 1) & 1;
      const int off = ((it + 1) >> 4) * (128 * D_DIM) + ((it + 1) & 15) * 32;
      gll16(Agb + off,              &As[nb][ldst]);
      gll16(Agb + off + 64 * D_DIM, &As[nb][2048 + ldst]);
    }
    const int cb = it & 1;
    const int ki = it & 15;
    bf16x8 af[4], wf[4];
#pragma unroll
    for (int r = 0; r < 4; r++) af[r] = *(const bf16x8*)&As[cb][ra + r * 512];
#pragma unroll
    for (int r = 0; r < 4; r++) {
      const int row = wno * 64 + r * 16 + l15;
      wf[r] = *(const bf16x8*)&Wlds[row * D_DIM + (((ki * 4 + quad) ^ (l15 & 7)) * 8)];
    }
#pragma unroll
    for (int rm = 0; rm < 4; rm++)
#pragma unroll
      for (int rn = 0; rn < 4; rn++)
        acc[rm][rn] = __builtin_amdgcn_mfma_f32_16x16x32_bf16(
            af[rm], wf[rn], acc[rm][rn], 0, 0, 0);

    if (ki == 15) {    // epilogue for m-tile mi (overlaps next-m A prefetch)
      const int mi = it >> 4;
#pragma unroll
      for (int rm = 0; rm < 4; rm++) {
#pragma unroll
        for (int reg = 0; reg < 4; reg++) {
          const int bl = wm * 64 + rm * 16 + quad * 4 + reg;  // C/D row = M
          const int b = mi * 128 + bl;
          const int tgt = targets[b];  // uniform across 16-lane group
          float s = 0.0f;
#pragma unroll
          for (int rn = 0; rn < 4; rn++) {
            const int c = tile_n + wno * 64 + rn * 16 + l15;  // C/D col = N
            const float cosv = acc[rm][rn][reg] * wiv[rn];
            float logit = Sc * cosv;
            if (c == tgt) {
              const float sine = sqrtf(fmaxf(1.0f - cosv * cosv, 0.0f));
              float phi = cosv * COSM - sine * SINM;
              phi = (cosv > THc) ? phi : (cosv - MMc);
              logit = Sc * phi;
              tlogit[b] = logit;  // exactly one lane in the grid owns (b,tgt)
            }
            s += (c < C_CLS) ? __expf(logit - 30.0f) : 0.0f;  // mask pad cols
          }
          s += __shfl_xor(s, 1);
          s += __shfl_xor(s, 2);
          s += __shfl_xor(s, 4);
          s += __shfl_xor(s, 8);
          if (l15 == 0) atomicAdd(psum + b, s);
          acc[rm][reg == 3 ? 0 : 0] = acc[rm][0];  // no-op keeper (see reset below)
        }
#pragma unroll
        for (int rn = 0; rn < 4; rn++) acc[rm][rn] = vzero;  // reset for next m
      }
    }
  }
}

__global__ void finalize_loss(const float* __restrict__ psum,
                              const float* __restrict__ tlogit,
                              float* __restrict__ out)
{
  const int tid = threadIdx.x;
  float s = 0.0f;
  for (int i = tid; i < B_ROWS; i += 256)
    s += 30.0f + logf(psum[i]) - tlogit[i];   // logsumexp - target logit
#pragma unroll
  for (int m = 1; m < 64; m <<= 1) s += __shfl_xor(s, m);
  __shared__ float red[4];
  if ((tid & 63) == 0) red[tid >> 6] = s;
  __syncthreads();
  if (tid == 0) out[0] = (red[0] + red[1] + red[2] + red[3]) * (1.0f / B_ROWS);
}

extern "C" void kernel_launch(void* const* d_in, const int* in_sizes, int n_in,
                              void* d_out, int out_size, void* d_ws, size_t ws_size,
                              hipStream_t stream) {
  const float* feat = (const float*)d_in[0];
  const float* wt   = (const float*)d_in[1];
  const int*   tgt  = (const int*)d_in[2];
  float* out = (float*)d_out;
  char* ws = (char*)d_ws;

  // ws layout: fn 1 MB | psum 4 KB | tlogit 4 KB
  u16* fn = (u16*)ws;
  float* psum = (float*)(ws + (size_t)B_ROWS * D_DIM * 2);
  float* tlogit = psum + B_ROWS;

  hipMemsetAsync(psum, 0, B_ROWS * sizeof(float), stream);
  norm_feat_kernel<<<B_ROWS / 4, 256, 0, stream>>>(feat, fn);
  arc_gemm<<<N_TILES, 256, 0, stream>>>(fn, wt, tgt, psum, tlogit);
  finalize_loss<<<1, 256, 0, stream>>>(psum, tlogit, out);
}